// Round 4
// baseline (253.223 us; speedup 1.0000x reference)
//
#include <hip/hip_runtime.h>
#include <stdint.h>

// Problem constants (B,N,D)=(4,2048,256), H=4, DA=DL=64, NUM_BUCKETS=128
#define BB 4
#define NN 2048
#define DD 256
#define HH 4

typedef __attribute__((ext_vector_type(8))) __bf16 bf16x8;
typedef __attribute__((ext_vector_type(4))) float f32x4;
typedef __attribute__((ext_vector_type(8))) unsigned short u16x8;
typedef __attribute__((ext_vector_type(4))) unsigned short u16x4;

__device__ __forceinline__ unsigned short f2bf(float f) {
  union { float f; uint32_t u; } v; v.f = f;
  uint32_t r = v.u + 0x7fffu + ((v.u >> 16) & 1u);   // RNE
  return (unsigned short)(r >> 16);
}
__device__ __forceinline__ bf16x8 ld8(const unsigned short* p) {
  return __builtin_bit_cast(bf16x8, *(const u16x8*)p);
}
__device__ __forceinline__ f32x4 mfma16(bf16x8 a, bf16x8 b, f32x4 c) {
  return __builtin_amdgcn_mfma_f32_16x16x32_bf16(a, b, c, 0, 0, 0);
}
__device__ __forceinline__ float silu_f(float x) {
  return x / (1.0f + __expf(-x));
}

// ---------------- K0: weight convert + transpose to bf16 ----------------
// Wu_t[f][d] = bf16(W_uvqk[d][f])  (1024 x 256)
// Wo_t[f][d] = bf16(W_o[d][f])     (256 x 256)
__global__ __launch_bounds__(256) void k_prep_w(const float* __restrict__ Wu,
                                                const float* __restrict__ Wo,
                                                unsigned short* __restrict__ Wu_t,
                                                unsigned short* __restrict__ Wo_t) {
  int idx = blockIdx.x * 256 + threadIdx.x;
  if (idx < 1024 * 256) {
    int f = idx >> 8, d = idx & 255;
    Wu_t[idx] = f2bf(Wu[d * 1024 + f]);
  } else {
    int i = idx - 1024 * 256;
    int f = i >> 8, d = i & 255;
    Wo_t[i] = f2bf(Wo[d * 256 + f]);
  }
}

// ---------------- K1: input LayerNorm -> nx (bf16) ----------------
__global__ __launch_bounds__(256) void k_ln_in(const float* __restrict__ x,
                                               const float* __restrict__ g,
                                               const float* __restrict__ be,
                                               unsigned short* __restrict__ nx) {
  int wave = threadIdx.x >> 6, lane = threadIdx.x & 63;
  int row = blockIdx.x * 4 + wave;
  const float4 v = *(const float4*)(x + (size_t)row * DD + lane * 4);
  float s = v.x + v.y + v.z + v.w;
  float sq = v.x * v.x + v.y * v.y + v.z * v.z + v.w * v.w;
  #pragma unroll
  for (int o = 32; o; o >>= 1) { s += __shfl_xor(s, o); sq += __shfl_xor(sq, o); }
  float mean = s * (1.0f / DD);
  float var = sq * (1.0f / DD) - mean * mean;
  float rstd = rsqrtf(var + 1e-5f);
  const float4 gv = *(const float4*)(g + lane * 4);
  const float4 bv = *(const float4*)(be + lane * 4);
  u16x4 o4;
  o4[0] = f2bf((v.x - mean) * rstd * gv.x + bv.x);
  o4[1] = f2bf((v.y - mean) * rstd * gv.y + bv.y);
  o4[2] = f2bf((v.z - mean) * rstd * gv.z + bv.z);
  o4[3] = f2bf((v.w - mean) * rstd * gv.w + bv.w);
  *(u16x4*)(nx + (size_t)row * DD + lane * 4) = o4;
}

// ---------------- K2: GEMM nx(8192x256) @ Wu_t^T -> silu -> scatter u,v,q,k ----
// 128x128 tile, BK=64, 4 waves each 64x64. LDS padded rows (72 shorts = 144B, 16B-aligned).
__global__ __launch_bounds__(256) void k_gemm_uvqk(const unsigned short* __restrict__ nx,
                                                   const unsigned short* __restrict__ Wu_t,
                                                   const float* __restrict__ b_uvqk,
                                                   float* __restrict__ u,
                                                   unsigned short* __restrict__ v_tmp,
                                                   unsigned short* __restrict__ q_t,
                                                   unsigned short* __restrict__ k_t) {
  __shared__ unsigned short As[128 * 72];
  __shared__ unsigned short Bs[128 * 72];
  int tid = threadIdx.x, lane = tid & 63, w = tid >> 6;
  int wr = w >> 1, wc = w & 1, c = lane & 15, g = lane >> 4;
  int rblk = blockIdx.x >> 3, cblk = blockIdx.x & 7;
  int R0 = rblk * 128, C0 = cblk * 128;
  f32x4 acc[4][4] = {};
  for (int ks = 0; ks < 4; ++ks) {
    __syncthreads();
    #pragma unroll
    for (int it = 0; it < 4; ++it) {
      int task = tid + it * 256, row = task >> 3, ch = task & 7;
      *(u16x8*)(As + row * 72 + ch * 8) =
          *(const u16x8*)(nx + (size_t)(R0 + row) * 256 + ks * 64 + ch * 8);
      *(u16x8*)(Bs + row * 72 + ch * 8) =
          *(const u16x8*)(Wu_t + (size_t)(C0 + row) * 256 + ks * 64 + ch * 8);
    }
    __syncthreads();
    #pragma unroll
    for (int kk = 0; kk < 2; ++kk) {
      int koff = kk * 32 + g * 8;
      bf16x8 af[4], bfr[4];
      #pragma unroll
      for (int rt = 0; rt < 4; ++rt) af[rt] = ld8(As + (wr * 64 + rt * 16 + c) * 72 + koff);
      #pragma unroll
      for (int ct = 0; ct < 4; ++ct) bfr[ct] = ld8(Bs + (wc * 64 + ct * 16 + c) * 72 + koff);
      #pragma unroll
      for (int rt = 0; rt < 4; ++rt)
        #pragma unroll
        for (int ct = 0; ct < 4; ++ct)
          acc[rt][ct] = mfma16(af[rt], bfr[ct], acc[rt][ct]);
    }
  }
  // epilogue: silu + scatter. F<256:u fp32; [256,512):v_tmp bf16; [512,768):q_t; [768,1024):k_t
  #pragma unroll
  for (int rt = 0; rt < 4; ++rt) {
    #pragma unroll
    for (int ct = 0; ct < 4; ++ct) {
      int F = C0 + wc * 64 + ct * 16 + c;
      float bb = b_uvqk[F];
      #pragma unroll
      for (int rr = 0; rr < 4; ++rr) {
        int R = R0 + wr * 64 + rt * 16 + g * 4 + rr;
        float pre = acc[rt][ct][rr] + bb;
        float sv = silu_f(pre);
        int b = R >> 11, n = R & 2047;
        if (F < 256) {
          u[(size_t)R * 256 + F] = sv;
        } else if (F < 512) {
          v_tmp[(size_t)R * 256 + (F - 256)] = f2bf(sv);
        } else if (F < 768) {
          int h = (F - 512) >> 6, d = (F - 512) & 63;
          q_t[((size_t)((b << 2) + h) * 2048 + n) * 64 + d] = f2bf(sv);
        } else {
          int h = (F - 768) >> 6, d = (F - 768) & 63;
          k_t[((size_t)((b << 2) + h) * 2048 + n) * 64 + d] = f2bf(sv);
        }
      }
    }
  }
}

// ---------------- K2b: transpose v_tmp (B,N,H,64) -> v_t (B,H,64,N) ----------------
__global__ __launch_bounds__(256) void k_vtrans(const unsigned short* __restrict__ v_tmp,
                                                unsigned short* __restrict__ v_t) {
  __shared__ unsigned short T[64 * 72];
  int bi = blockIdx.x;
  int nch = bi & 31, h = (bi >> 5) & 3, b = bi >> 7;
  int n0 = nch * 64;
  int tid = threadIdx.x;
  #pragma unroll
  for (int it = 0; it < 2; ++it) {
    int task = tid + it * 256;
    int i = task >> 3, ch = task & 7;
    *(u16x8*)(T + i * 72 + ch * 8) =
        *(const u16x8*)(v_tmp + ((size_t)(b * 2048 + n0 + i)) * 256 + h * 64 + ch * 8);
  }
  __syncthreads();
  #pragma unroll
  for (int it = 0; it < 2; ++it) {
    int task = tid + it * 256;
    int d = task >> 3, ch = task & 7;
    u16x8 ov;
    #pragma unroll
    for (int uu = 0; uu < 8; ++uu) ov[uu] = T[(ch * 8 + uu) * 72 + d];
    *(u16x8*)(v_t + ((size_t)((b * 4 + h) * 64 + d)) * 2048 + n0 + ch * 8) = ov;
  }
}

// ---------------- K3: fused attention (no softmax: silu(qk+bias)/N, causal+len mask) ----
// Block = 256 thr = 4 waves; wave w = head w; q-tile = 16 rows; KV step = 64.
// bias tile (head-independent) computed cooperatively once per step into LDS.
__global__ __launch_bounds__(256) void k_attn(const unsigned short* __restrict__ q_t,
                                              const unsigned short* __restrict__ k_t,
                                              const unsigned short* __restrict__ v_t,
                                              const int* __restrict__ ts_raw,
                                              const int* __restrict__ lens_raw,
                                              const float* __restrict__ w_pos,
                                              const float* __restrict__ w_ts,
                                              float* __restrict__ av_out) {
  __shared__ float bias_s[16 * 68];
  __shared__ float P_s[4][16 * 68];
  int tid = threadIdx.x, lane = tid & 63, h = tid >> 6;
  int c = lane & 15, g = lane >> 4;
  int bi = blockIdx.x;
  int b = bi & 3, qt = 127 - (bi >> 2);     // big tiles first
  int n0 = qt * 16;
  // int64-vs-int32 auto-detect: true lengths are >=1, so odd int32 words are 0 iff int64
  int stride = (lens_raw[1] == 0 && lens_raw[3] == 0) ? 2 : 1;
  int Lb = lens_raw[b * stride];
  const int* tsb = ts_raw + (size_t)b * 2048 * stride;
  const unsigned short* qp = q_t + (size_t)(b * 4 + h) * 2048 * 64;
  const unsigned short* kp = k_t + (size_t)(b * 4 + h) * 2048 * 64;
  const unsigned short* vp = v_t + (size_t)(b * 4 + h) * 64 * 2048;

  bf16x8 qf[2];
  qf[0] = ld8(qp + (size_t)(n0 + c) * 64 + g * 8);
  qf[1] = ld8(qp + (size_t)(n0 + c) * 64 + 32 + g * 8);
  f32x4 av[4] = {};
  int m_end = min(n0 + 16, Lb);
  for (int m0 = 0; m0 < m_end; m0 += 64) {
    // --- cooperative bias tile (16 x 64) ---
    #pragma unroll
    for (int it = 0; it < 4; ++it) {
      int e = tid + it * 256;
      int nl = e >> 6, ml = e & 63;
      int n = n0 + nl, m = m0 + ml;
      int dtv = tsb[n * stride] - tsb[m * stride];
      float ad = fmaxf(fabsf((float)dtv), 1.0f);
      int bk = (int)(logf(ad) / 0.301f);
      bk = bk > 128 ? 128 : bk;
      bias_s[nl * 68 + ml] = w_pos[n - m + 2047] + w_ts[bk];
    }
    __syncthreads();
    // --- qk^T: 16x64 per wave ---
    f32x4 s[4] = {};
    #pragma unroll
    for (int mt = 0; mt < 4; ++mt) {
      bf16x8 kf0 = ld8(kp + (size_t)(m0 + mt * 16 + c) * 64 + g * 8);
      bf16x8 kf1 = ld8(kp + (size_t)(m0 + mt * 16 + c) * 64 + 32 + g * 8);
      s[mt] = mfma16(qf[0], kf0, s[mt]);
      s[mt] = mfma16(qf[1], kf1, s[mt]);
    }
    // --- bias + silu + mask -> P (fp32, per-wave LDS tile) ---
    float* Pw = P_s[h];
    #pragma unroll
    for (int mt = 0; mt < 4; ++mt) {
      #pragma unroll
      for (int rr = 0; rr < 4; ++rr) {
        int nl = g * 4 + rr, ml = mt * 16 + c;
        float sv = s[mt][rr] + bias_s[nl * 68 + ml];
        int n = n0 + nl, m = m0 + ml;
        float p = 0.0f;
        if (m <= n && m < Lb) p = silu_f(sv) * (1.0f / 2048.0f);
        Pw[nl * 68 + ml] = p;
      }
    }
    // --- PV: av(16x64) += P(16x64) @ V(64x64); A-frag via same-wave LDS round-trip ---
    #pragma unroll
    for (int kk = 0; kk < 2; ++kk) {
      f32x4 plo = *(const f32x4*)(Pw + c * 68 + kk * 32 + g * 8);
      f32x4 phi = *(const f32x4*)(Pw + c * 68 + kk * 32 + g * 8 + 4);
      union { bf16x8 v; unsigned short e[8]; } pu;
      pu.e[0] = f2bf(plo.x); pu.e[1] = f2bf(plo.y);
      pu.e[2] = f2bf(plo.z); pu.e[3] = f2bf(plo.w);
      pu.e[4] = f2bf(phi.x); pu.e[5] = f2bf(phi.y);
      pu.e[6] = f2bf(phi.z); pu.e[7] = f2bf(phi.w);
      #pragma unroll
      for (int dt = 0; dt < 4; ++dt) {
        bf16x8 vf = ld8(vp + (size_t)(dt * 16 + c) * 2048 + m0 + kk * 32 + g * 8);
        av[dt] = mfma16(pu.v, vf, av[dt]);
      }
    }
    __syncthreads();
  }
  #pragma unroll
  for (int dt = 0; dt < 4; ++dt)
    #pragma unroll
    for (int rr = 0; rr < 4; ++rr) {
      int n = n0 + g * 4 + rr;
      av_out[((size_t)b * 2048 + n) * 256 + h * 64 + dt * 16 + c] = av[dt][rr];
    }
}

// ---------------- K4: LayerNorm(av) * u -> a2 (bf16) ----------------
__global__ __launch_bounds__(256) void k_ln_attn(const float* __restrict__ av,
                                                 const float* __restrict__ u,
                                                 const float* __restrict__ g,
                                                 const float* __restrict__ be,
                                                 unsigned short* __restrict__ a2) {
  int wave = threadIdx.x >> 6, lane = threadIdx.x & 63;
  int row = blockIdx.x * 4 + wave;
  const float4 v = *(const float4*)(av + (size_t)row * DD + lane * 4);
  float s = v.x + v.y + v.z + v.w;
  float sq = v.x * v.x + v.y * v.y + v.z * v.z + v.w * v.w;
  #pragma unroll
  for (int o = 32; o; o >>= 1) { s += __shfl_xor(s, o); sq += __shfl_xor(sq, o); }
  float mean = s * (1.0f / DD);
  float var = sq * (1.0f / DD) - mean * mean;
  float rstd = rsqrtf(var + 1e-5f);
  const float4 gv = *(const float4*)(g + lane * 4);
  const float4 bv = *(const float4*)(be + lane * 4);
  const float4 uv = *(const float4*)(u + (size_t)row * DD + lane * 4);
  u16x4 o4;
  o4[0] = f2bf(((v.x - mean) * rstd * gv.x + bv.x) * uv.x);
  o4[1] = f2bf(((v.y - mean) * rstd * gv.y + bv.y) * uv.y);
  o4[2] = f2bf(((v.z - mean) * rstd * gv.z + bv.z) * uv.z);
  o4[3] = f2bf(((v.w - mean) * rstd * gv.w + bv.w) * uv.w);
  *(u16x4*)(a2 + (size_t)row * DD + lane * 4) = o4;
}

// ---------------- K5: out GEMM a2(8192x256) @ Wo_t^T + b_o + x, row-mask ---------
__global__ __launch_bounds__(256) void k_gemm_out(const unsigned short* __restrict__ a2,
                                                  const unsigned short* __restrict__ Wo_t,
                                                  const float* __restrict__ b_o,
                                                  const float* __restrict__ x,
                                                  const int* __restrict__ lens_raw,
                                                  float* __restrict__ out) {
  __shared__ unsigned short As[64 * 72];
  __shared__ unsigned short Bs[64 * 72];
  int tid = threadIdx.x, lane = tid & 63, w = tid >> 6;
  int wr = w >> 1, wc = w & 1, c = lane & 15, g = lane >> 4;
  int rblk = blockIdx.x >> 2, cblk = blockIdx.x & 3;
  int R0 = rblk * 64, C0 = cblk * 64;
  int stride = (lens_raw[1] == 0 && lens_raw[3] == 0) ? 2 : 1;
  f32x4 acc[2][2] = {};
  for (int ks = 0; ks < 4; ++ks) {
    __syncthreads();
    #pragma unroll
    for (int it = 0; it < 2; ++it) {
      int task = tid + it * 256, row = task >> 3, ch = task & 7;
      *(u16x8*)(As + row * 72 + ch * 8) =
          *(const u16x8*)(a2 + (size_t)(R0 + row) * 256 + ks * 64 + ch * 8);
      *(u16x8*)(Bs + row * 72 + ch * 8) =
          *(const u16x8*)(Wo_t + (size_t)(C0 + row) * 256 + ks * 64 + ch * 8);
    }
    __syncthreads();
    #pragma unroll
    for (int kk = 0; kk < 2; ++kk) {
      int koff = kk * 32 + g * 8;
      bf16x8 af[2], bfr[2];
      #pragma unroll
      for (int rt = 0; rt < 2; ++rt) af[rt] = ld8(As + (wr * 32 + rt * 16 + c) * 72 + koff);
      #pragma unroll
      for (int ct = 0; ct < 2; ++ct) bfr[ct] = ld8(Bs + (wc * 32 + ct * 16 + c) * 72 + koff);
      #pragma unroll
      for (int rt = 0; rt < 2; ++rt)
        #pragma unroll
        for (int ct = 0; ct < 2; ++ct)
          acc[rt][ct] = mfma16(af[rt], bfr[ct], acc[rt][ct]);
    }
  }
  #pragma unroll
  for (int rt = 0; rt < 2; ++rt) {
    #pragma unroll
    for (int ct = 0; ct < 2; ++ct) {
      int F = C0 + wc * 32 + ct * 16 + c;
      float bo = b_o[F];
      #pragma unroll
      for (int rr = 0; rr < 4; ++rr) {
        int R = R0 + wr * 32 + rt * 16 + g * 4 + rr;
        int b = R >> 11, n = R & 2047;
        int Lb = lens_raw[b * stride];
        float val = acc[rt][ct][rr] + bo + x[(size_t)R * 256 + F];
        out[(size_t)R * 256 + F] = (n < Lb) ? val : 0.0f;
      }
    }
  }
}

// ---------------- launch ----------------
extern "C" void kernel_launch(void* const* d_in, const int* in_sizes, int n_in,
                              void* d_out, int out_size, void* d_ws, size_t ws_size,
                              hipStream_t stream) {
  const float* x        = (const float*)d_in[0];
  const float* W_uvqk   = (const float*)d_in[1];
  const float* b_uvqk   = (const float*)d_in[2];
  const float* W_o      = (const float*)d_in[3];
  const float* b_o      = (const float*)d_in[4];
  const float* ln_in_g  = (const float*)d_in[5];
  const float* ln_in_b  = (const float*)d_in[6];
  const float* ln_attn_g= (const float*)d_in[7];
  const float* ln_attn_b= (const float*)d_in[8];
  const float* w_pos    = (const float*)d_in[9];
  const float* w_ts     = (const float*)d_in[10];
  const int*   lengths  = (const int*)d_in[11];
  const int*   tstamps  = (const int*)d_in[12];
  float* out = (float*)d_out;

  char* ws = (char*)d_ws;
  size_t off = 0;
  auto alloc = [&](size_t bytes) -> void* {
    void* p = ws + off;
    off += (bytes + 255) & ~(size_t)255;
    return p;
  };
  unsigned short* Wu_t  = (unsigned short*)alloc(1024 * 256 * 2);
  unsigned short* Wo_t  = (unsigned short*)alloc(256 * 256 * 2);
  unsigned short* nx    = (unsigned short*)alloc((size_t)8192 * 256 * 2);
  float*          u     = (float*)alloc((size_t)8192 * 256 * 4);
  unsigned short* v_tmp = (unsigned short*)alloc((size_t)8192 * 256 * 2);
  unsigned short* v_t   = (unsigned short*)alloc((size_t)8192 * 256 * 2);
  unsigned short* q_t   = (unsigned short*)alloc((size_t)8192 * 256 * 2);
  unsigned short* k_t   = (unsigned short*)alloc((size_t)8192 * 256 * 2);
  float*          av    = (float*)alloc((size_t)8192 * 256 * 4);
  unsigned short* a2    = (unsigned short*)alloc((size_t)8192 * 256 * 2);

  k_prep_w<<<1280, 256, 0, stream>>>(W_uvqk, W_o, Wu_t, Wo_t);
  k_ln_in<<<2048, 256, 0, stream>>>(x, ln_in_g, ln_in_b, nx);
  k_gemm_uvqk<<<512, 256, 0, stream>>>(nx, Wu_t, b_uvqk, u, v_tmp, q_t, k_t);
  k_vtrans<<<512, 256, 0, stream>>>(v_tmp, v_t);
  k_attn<<<512, 256, 0, stream>>>(q_t, k_t, v_t, tstamps, lengths, w_pos, w_ts, av);
  k_ln_attn<<<2048, 256, 0, stream>>>(av, u, ln_attn_g, ln_attn_b, a2);
  k_gemm_out<<<512, 256, 0, stream>>>(a2, Wo_t, b_o, x, lengths, out);
}

// Round 8
// 237.090 us; speedup vs baseline: 1.0680x; 1.0680x over previous
//
#include <hip/hip_runtime.h>
#include <stdint.h>

// Problem constants (B,N,D)=(4,2048,256), H=4, DA=DL=64, NUM_BUCKETS=128
#define BB 4
#define NN 2048
#define DD 256
#define HH 4

typedef __attribute__((ext_vector_type(8))) __bf16 bf16x8;
typedef __attribute__((ext_vector_type(4))) float f32x4;
typedef __attribute__((ext_vector_type(8))) unsigned short u16x8;
typedef __attribute__((ext_vector_type(4))) unsigned short u16x4;

__device__ __forceinline__ unsigned short f2bf(float f) {
  union { float f; uint32_t u; } v; v.f = f;
  uint32_t r = v.u + 0x7fffu + ((v.u >> 16) & 1u);   // RNE
  return (unsigned short)(r >> 16);
}
__device__ __forceinline__ bf16x8 ld8(const unsigned short* p) {
  return __builtin_bit_cast(bf16x8, *(const u16x8*)p);
}
__device__ __forceinline__ f32x4 mfma16(bf16x8 a, bf16x8 b, f32x4 c) {
  return __builtin_amdgcn_mfma_f32_16x16x32_bf16(a, b, c, 0, 0, 0);
}
__device__ __forceinline__ float silu_f(float x) {
  return x / (1.0f + __expf(-x));
}

// ---------------- K0: weight convert + transpose to bf16 (LDS-tiled) ----------------
// Wu_t[f][d] = bf16(W_uvqk[d][f])  (1024 x 256);  Wo_t[f][d] = bf16(W_o[d][f]) (256 x 256)
// grid: 64 blocks for Wu (16 f-tiles x 4 d-tiles of 64x64) + 16 blocks for Wo.
__global__ __launch_bounds__(256) void k_prep_w(const float* __restrict__ Wu,
                                                const float* __restrict__ Wo,
                                                unsigned short* __restrict__ Wu_t,
                                                unsigned short* __restrict__ Wo_t) {
  __shared__ float T[64][65];
  int bi = blockIdx.x;
  const float* src; unsigned short* dst; int F, f0, d0;
  if (bi < 64) { src = Wu; dst = Wu_t; F = 1024; f0 = (bi >> 2) * 64; d0 = (bi & 3) * 64; }
  else { int j = bi - 64; src = Wo; dst = Wo_t; F = 256; f0 = (j >> 2) * 64; d0 = (j & 3) * 64; }
  int t = threadIdx.x;
  int li = t >> 4;            // 0..15
  int lj = (t & 15) * 4;      // 0,4,..,60
  #pragma unroll
  for (int it = 0; it < 4; ++it) {
    int d = li + it * 16;
    float4 v = *(const float4*)(src + (size_t)(d0 + d) * F + f0 + lj);
    T[lj + 0][d] = v.x; T[lj + 1][d] = v.y; T[lj + 2][d] = v.z; T[lj + 3][d] = v.w;
  }
  __syncthreads();
  #pragma unroll
  for (int it = 0; it < 4; ++it) {
    int f = li + it * 16;
    u16x4 o;
    o[0] = f2bf(T[f][lj + 0]); o[1] = f2bf(T[f][lj + 1]);
    o[2] = f2bf(T[f][lj + 2]); o[3] = f2bf(T[f][lj + 3]);
    *(u16x4*)(dst + (size_t)(f0 + f) * 256 + d0 + lj) = o;
  }
}

// ---------------- K1: input LayerNorm -> nx (bf16) ----------------
__global__ __launch_bounds__(256) void k_ln_in(const float* __restrict__ x,
                                               const float* __restrict__ g,
                                               const float* __restrict__ be,
                                               unsigned short* __restrict__ nx) {
  int wave = threadIdx.x >> 6, lane = threadIdx.x & 63;
  int row = blockIdx.x * 4 + wave;
  const float4 v = *(const float4*)(x + (size_t)row * DD + lane * 4);
  float s = v.x + v.y + v.z + v.w;
  float sq = v.x * v.x + v.y * v.y + v.z * v.z + v.w * v.w;
  #pragma unroll
  for (int o = 32; o; o >>= 1) { s += __shfl_xor(s, o); sq += __shfl_xor(sq, o); }
  float mean = s * (1.0f / DD);
  float var = sq * (1.0f / DD) - mean * mean;
  float rstd = rsqrtf(var + 1e-5f);
  const float4 gv = *(const float4*)(g + lane * 4);
  const float4 bv = *(const float4*)(be + lane * 4);
  u16x4 o4;
  o4[0] = f2bf((v.x - mean) * rstd * gv.x + bv.x);
  o4[1] = f2bf((v.y - mean) * rstd * gv.y + bv.y);
  o4[2] = f2bf((v.z - mean) * rstd * gv.z + bv.z);
  o4[3] = f2bf((v.w - mean) * rstd * gv.w + bv.w);
  *(u16x4*)(nx + (size_t)row * DD + lane * 4) = o4;
}

// ---------------- K2: GEMM nx(8192x256) @ Wu_t^T -> silu -> scatter u,v,q,k ----
__global__ __launch_bounds__(256) void k_gemm_uvqk(const unsigned short* __restrict__ nx,
                                                   const unsigned short* __restrict__ Wu_t,
                                                   const float* __restrict__ b_uvqk,
                                                   float* __restrict__ u,
                                                   unsigned short* __restrict__ v_tmp,
                                                   unsigned short* __restrict__ q_t,
                                                   unsigned short* __restrict__ k_t) {
  __shared__ unsigned short As[128 * 72];
  __shared__ unsigned short Bs[128 * 72];
  int tid = threadIdx.x, lane = tid & 63, w = tid >> 6;
  int wr = w >> 1, wc = w & 1, c = lane & 15, g = lane >> 4;
  int rblk = blockIdx.x >> 3, cblk = blockIdx.x & 7;
  int R0 = rblk * 128, C0 = cblk * 128;
  f32x4 acc[4][4] = {};
  for (int ks = 0; ks < 4; ++ks) {
    __syncthreads();
    #pragma unroll
    for (int it = 0; it < 4; ++it) {
      int task = tid + it * 256, row = task >> 3, ch = task & 7;
      *(u16x8*)(As + row * 72 + ch * 8) =
          *(const u16x8*)(nx + (size_t)(R0 + row) * 256 + ks * 64 + ch * 8);
      *(u16x8*)(Bs + row * 72 + ch * 8) =
          *(const u16x8*)(Wu_t + (size_t)(C0 + row) * 256 + ks * 64 + ch * 8);
    }
    __syncthreads();
    #pragma unroll
    for (int kk = 0; kk < 2; ++kk) {
      int koff = kk * 32 + g * 8;
      bf16x8 af[4], bfr[4];
      #pragma unroll
      for (int rt = 0; rt < 4; ++rt) af[rt] = ld8(As + (wr * 64 + rt * 16 + c) * 72 + koff);
      #pragma unroll
      for (int ct = 0; ct < 4; ++ct) bfr[ct] = ld8(Bs + (wc * 64 + ct * 16 + c) * 72 + koff);
      #pragma unroll
      for (int rt = 0; rt < 4; ++rt)
        #pragma unroll
        for (int ct = 0; ct < 4; ++ct)
          acc[rt][ct] = mfma16(af[rt], bfr[ct], acc[rt][ct]);
    }
  }
  #pragma unroll
  for (int rt = 0; rt < 4; ++rt) {
    #pragma unroll
    for (int ct = 0; ct < 4; ++ct) {
      int F = C0 + wc * 64 + ct * 16 + c;
      float bb = b_uvqk[F];
      #pragma unroll
      for (int rr = 0; rr < 4; ++rr) {
        int R = R0 + wr * 64 + rt * 16 + g * 4 + rr;
        float pre = acc[rt][ct][rr] + bb;
        float sv = silu_f(pre);
        int b = R >> 11, n = R & 2047;
        if (F < 256) {
          u[(size_t)R * 256 + F] = sv;
        } else if (F < 512) {
          v_tmp[(size_t)R * 256 + (F - 256)] = f2bf(sv);
        } else if (F < 768) {
          int h = (F - 512) >> 6, d = (F - 512) & 63;
          q_t[((size_t)((b << 2) + h) * 2048 + n) * 64 + d] = f2bf(sv);
        } else {
          int h = (F - 768) >> 6, d = (F - 768) & 63;
          k_t[((size_t)((b << 2) + h) * 2048 + n) * 64 + d] = f2bf(sv);
        }
      }
    }
  }
}

// ---------------- K2b: transpose v_tmp (B,N,H,64) -> v_t (B,H,64,N) ----------------
__global__ __launch_bounds__(256) void k_vtrans(const unsigned short* __restrict__ v_tmp,
                                                unsigned short* __restrict__ v_t) {
  __shared__ unsigned short T[64 * 72];
  int bi = blockIdx.x;
  int nch = bi & 31, h = (bi >> 5) & 3, b = bi >> 7;
  int n0 = nch * 64;
  int tid = threadIdx.x;
  #pragma unroll
  for (int it = 0; it < 2; ++it) {
    int task = tid + it * 256;
    int i = task >> 3, ch = task & 7;
    *(u16x8*)(T + i * 72 + ch * 8) =
        *(const u16x8*)(v_tmp + ((size_t)(b * 2048 + n0 + i)) * 256 + h * 64 + ch * 8);
  }
  __syncthreads();
  #pragma unroll
  for (int it = 0; it < 2; ++it) {
    int task = tid + it * 256;
    int d = task >> 3, ch = task & 7;
    u16x8 ov;
    #pragma unroll
    for (int uu = 0; uu < 8; ++uu) ov[uu] = T[(ch * 8 + uu) * 72 + d];
    *(u16x8*)(v_t + ((size_t)((b * 4 + h) * 64 + d)) * 2048 + n0 + ch * 8) = ov;
  }
}

// ---------------- K3: fused attention, barrier-free, split-K=2 ----------------
// silu(qk+bias)/N with causal+len mask; NO softmax (pure running sum -> no rescale).
// Block = 4 waves = 4 heads, one (b, 16-row q-tile, KV-chunk). Bias computed per-wave
// in registers at the MFMA C-fragment positions (hardware v_log_f32). No __syncthreads
// in the KV loop; P goes through a per-wave LDS tile (same-wave in-order LDS).
// chunk 0: KV [0, min(1024, m_end)); chunk 1 (qt>=64): KV [1024, m_end) -> avP1 packed.
__global__ __launch_bounds__(256) void k_attn(const unsigned short* __restrict__ q_t,
                                              const unsigned short* __restrict__ k_t,
                                              const unsigned short* __restrict__ v_t,
                                              const int* __restrict__ ts_raw,
                                              const int* __restrict__ lens_raw,
                                              const float* __restrict__ w_pos,
                                              const float* __restrict__ w_ts,
                                              float* __restrict__ avP0,
                                              float* __restrict__ avP1) {
  __shared__ unsigned short P_s[4][16 * 72];
  int tid = threadIdx.x, lane = tid & 63, h = tid >> 6;
  int c = lane & 15, g = lane >> 4;
  int bi = blockIdx.x;
  int b, qt, chunk;
  if (bi < 512) { chunk = 0; b = bi & 3; qt = 127 - (bi >> 2); }
  else { chunk = 1; int j = bi - 512; b = j & 3; qt = 127 - (j >> 2); }   // qt in [64,127]
  int n0 = qt * 16;
  // int64-vs-int32 auto-detect: true lengths are >=1, so odd int32 words are 0 iff int64
  int stride = (lens_raw[1] == 0 && lens_raw[3] == 0) ? 2 : 1;
  int Lb = lens_raw[b * stride];
  const int* tsb = ts_raw + (size_t)b * 2048 * stride;
  const unsigned short* qp = q_t + (size_t)(b * 4 + h) * 2048 * 64;
  const unsigned short* kp = k_t + (size_t)(b * 4 + h) * 2048 * 64;
  const unsigned short* vp = v_t + (size_t)(b * 4 + h) * 64 * 2048;

  int m_end = min(n0 + 16, Lb);
  int kv_lo = chunk ? 1024 : 0;
  int kv_hi = chunk ? m_end : min(m_end, 1024);

  bf16x8 qf0 = ld8(qp + (size_t)(n0 + c) * 64 + g * 8);
  bf16x8 qf1 = ld8(qp + (size_t)(n0 + c) * 64 + 32 + g * 8);
  int tn[4];
  #pragma unroll
  for (int rr = 0; rr < 4; ++rr) tn[rr] = tsb[(n0 + g * 4 + rr) * stride];
  unsigned short* Pw = &P_s[h][0];
  f32x4 av[4] = {};

  for (int m0 = kv_lo; m0 < kv_hi; m0 += 64) {
    // qk^T: 16x64 per wave
    f32x4 s[4] = {};
    #pragma unroll
    for (int mt = 0; mt < 4; ++mt) {
      const unsigned short* kr = kp + (size_t)(m0 + mt * 16 + c) * 64 + g * 8;
      s[mt] = mfma16(qf0, ld8(kr), s[mt]);
      s[mt] = mfma16(qf1, ld8(kr + 32), s[mt]);
    }
    // bias + silu + mask, in registers at C-frag positions -> bf16 -> per-wave LDS
    #pragma unroll
    for (int mt = 0; mt < 4; ++mt) {
      int m = m0 + mt * 16 + c;
      int tm = tsb[m * stride];
      #pragma unroll
      for (int rr = 0; rr < 4; ++rr) {
        int n = n0 + g * 4 + rr;
        int dtv = tn[rr] - tm;
        float ad = fmaxf(fabsf((float)dtv), 1.0f);
        int bk = (int)(__log2f(ad) * 2.3028145f);   // log(x)/0.301 == log2(x)*(ln2/0.301)
        bk = bk > 128 ? 128 : bk;
        float sv = s[mt][rr] + w_pos[n - m + 2047] + w_ts[bk];
        float p = (m <= n && m < Lb) ? silu_f(sv) * (1.0f / 2048.0f) : 0.0f;
        Pw[(g * 4 + rr) * 72 + mt * 16 + c] = f2bf(p);
      }
    }
    // PV: av(16x64) += P(16x64) @ V(64x64); A-frag via same-wave LDS round-trip
    #pragma unroll
    for (int kk = 0; kk < 2; ++kk) {
      bf16x8 pa = ld8(Pw + c * 72 + kk * 32 + g * 8);
      #pragma unroll
      for (int dt = 0; dt < 4; ++dt) {
        bf16x8 vf = ld8(vp + (size_t)(dt * 16 + c) * 2048 + m0 + kk * 32 + g * 8);
        av[dt] = mfma16(pa, vf, av[dt]);
      }
    }
  }

  if (chunk == 0) {
    #pragma unroll
    for (int dt = 0; dt < 4; ++dt)
      #pragma unroll
      for (int rr = 0; rr < 4; ++rr) {
        int n = n0 + g * 4 + rr;
        avP0[((size_t)(b * 2048 + n)) * 256 + h * 64 + dt * 16 + c] = av[dt][rr];
      }
  } else {
    #pragma unroll
    for (int dt = 0; dt < 4; ++dt)
      #pragma unroll
      for (int rr = 0; rr < 4; ++rr) {
        int n = n0 + g * 4 + rr;
        avP1[((size_t)(b * 1024 + (n - 1024))) * 256 + h * 64 + dt * 16 + c] = av[dt][rr];
      }
  }
}

// ---------------- K4: LayerNorm(avP0+avP1) * u -> a2 (bf16) ----------------
__global__ __launch_bounds__(256) void k_ln_attn(const float* __restrict__ avP0,
                                                 const float* __restrict__ avP1,
                                                 const float* __restrict__ u,
                                                 const float* __restrict__ g,
                                                 const float* __restrict__ be,
                                                 unsigned short* __restrict__ a2) {
  int wave = threadIdx.x >> 6, lane = threadIdx.x & 63;
  int row = blockIdx.x * 4 + wave;
  int n = row & 2047, b = row >> 11;
  float4 v = *(const float4*)(avP0 + (size_t)row * DD + lane * 4);
  if (n >= 1024) {
    const float4 w = *(const float4*)(avP1 + ((size_t)(b * 1024 + (n - 1024))) * DD + lane * 4);
    v.x += w.x; v.y += w.y; v.z += w.z; v.w += w.w;
  }
  float s = v.x + v.y + v.z + v.w;
  float sq = v.x * v.x + v.y * v.y + v.z * v.z + v.w * v.w;
  #pragma unroll
  for (int o = 32; o; o >>= 1) { s += __shfl_xor(s, o); sq += __shfl_xor(sq, o); }
  float mean = s * (1.0f / DD);
  float var = sq * (1.0f / DD) - mean * mean;
  float rstd = rsqrtf(var + 1e-5f);
  const float4 gv = *(const float4*)(g + lane * 4);
  const float4 bv = *(const float4*)(be + lane * 4);
  const float4 uv = *(const float4*)(u + (size_t)row * DD + lane * 4);
  u16x4 o4;
  o4[0] = f2bf(((v.x - mean) * rstd * gv.x + bv.x) * uv.x);
  o4[1] = f2bf(((v.y - mean) * rstd * gv.y + bv.y) * uv.y);
  o4[2] = f2bf(((v.z - mean) * rstd * gv.z + bv.z) * uv.z);
  o4[3] = f2bf(((v.w - mean) * rstd * gv.w + bv.w) * uv.w);
  *(u16x4*)(a2 + (size_t)row * DD + lane * 4) = o4;
}

// ---------------- K5: out GEMM a2(8192x256) @ Wo_t^T + b_o + x, row-mask ---------
__global__ __launch_bounds__(256) void k_gemm_out(const unsigned short* __restrict__ a2,
                                                  const unsigned short* __restrict__ Wo_t,
                                                  const float* __restrict__ b_o,
                                                  const float* __restrict__ x,
                                                  const int* __restrict__ lens_raw,
                                                  float* __restrict__ out) {
  __shared__ unsigned short As[64 * 72];
  __shared__ unsigned short Bs[64 * 72];
  int tid = threadIdx.x, lane = tid & 63, w = tid >> 6;
  int wr = w >> 1, wc = w & 1, c = lane & 15, g = lane >> 4;
  int rblk = blockIdx.x >> 2, cblk = blockIdx.x & 3;
  int R0 = rblk * 64, C0 = cblk * 64;
  int stride = (lens_raw[1] == 0 && lens_raw[3] == 0) ? 2 : 1;
  f32x4 acc[2][2] = {};
  for (int ks = 0; ks < 4; ++ks) {
    __syncthreads();
    #pragma unroll
    for (int it = 0; it < 2; ++it) {
      int task = tid + it * 256, row = task >> 3, ch = task & 7;
      *(u16x8*)(As + row * 72 + ch * 8) =
          *(const u16x8*)(a2 + (size_t)(R0 + row) * 256 + ks * 64 + ch * 8);
      *(u16x8*)(Bs + row * 72 + ch * 8) =
          *(const u16x8*)(Wo_t + (size_t)(C0 + row) * 256 + ks * 64 + ch * 8);
    }
    __syncthreads();
    #pragma unroll
    for (int kk = 0; kk < 2; ++kk) {
      int koff = kk * 32 + g * 8;
      bf16x8 af[2], bfr[2];
      #pragma unroll
      for (int rt = 0; rt < 2; ++rt) af[rt] = ld8(As + (wr * 32 + rt * 16 + c) * 72 + koff);
      #pragma unroll
      for (int ct = 0; ct < 2; ++ct) bfr[ct] = ld8(Bs + (wc * 32 + ct * 16 + c) * 72 + koff);
      #pragma unroll
      for (int rt = 0; rt < 2; ++rt)
        #pragma unroll
        for (int ct = 0; ct < 2; ++ct)
          acc[rt][ct] = mfma16(af[rt], bfr[ct], acc[rt][ct]);
    }
  }
  #pragma unroll
  for (int rt = 0; rt < 2; ++rt) {
    #pragma unroll
    for (int ct = 0; ct < 2; ++ct) {
      int F = C0 + wc * 32 + ct * 16 + c;
      float bo = b_o[F];
      #pragma unroll
      for (int rr = 0; rr < 4; ++rr) {
        int R = R0 + wr * 32 + rt * 16 + g * 4 + rr;
        int b = R >> 11, n = R & 2047;
        int Lb = lens_raw[b * stride];
        float val = acc[rt][ct][rr] + bo + x[(size_t)R * 256 + F];
        out[(size_t)R * 256 + F] = (n < Lb) ? val : 0.0f;
      }
    }
  }
}

// ---------------- launch ----------------
extern "C" void kernel_launch(void* const* d_in, const int* in_sizes, int n_in,
                              void* d_out, int out_size, void* d_ws, size_t ws_size,
                              hipStream_t stream) {
  const float* x        = (const float*)d_in[0];
  const float* W_uvqk   = (const float*)d_in[1];
  const float* b_uvqk   = (const float*)d_in[2];
  const float* W_o      = (const float*)d_in[3];
  const float* b_o      = (const float*)d_in[4];
  const float* ln_in_g  = (const float*)d_in[5];
  const float* ln_in_b  = (const float*)d_in[6];
  const float* ln_attn_g= (const float*)d_in[7];
  const float* ln_attn_b= (const float*)d_in[8];
  const float* w_pos    = (const float*)d_in[9];
  const float* w_ts     = (const float*)d_in[10];
  const int*   lengths  = (const int*)d_in[11];
  const int*   tstamps  = (const int*)d_in[12];
  float* out = (float*)d_out;

  char* ws = (char*)d_ws;
  size_t off = 0;
  auto alloc = [&](size_t bytes) -> void* {
    void* p = ws + off;
    off += (bytes + 255) & ~(size_t)255;
    return p;
  };
  unsigned short* Wu_t  = (unsigned short*)alloc(1024 * 256 * 2);
  unsigned short* Wo_t  = (unsigned short*)alloc(256 * 256 * 2);
  unsigned short* nx    = (unsigned short*)alloc((size_t)8192 * 256 * 2);  // reused as avP1 after gemm_uvqk
  float*          u     = (float*)alloc((size_t)8192 * 256 * 4);
  unsigned short* v_tmp = (unsigned short*)alloc((size_t)8192 * 256 * 2);
  unsigned short* v_t   = (unsigned short*)alloc((size_t)8192 * 256 * 2);
  unsigned short* q_t   = (unsigned short*)alloc((size_t)8192 * 256 * 2);
  unsigned short* k_t   = (unsigned short*)alloc((size_t)8192 * 256 * 2);
  float*          avP0  = (float*)alloc((size_t)8192 * 256 * 4);
  unsigned short* a2    = (unsigned short*)alloc((size_t)8192 * 256 * 2);
  float*          avP1  = (float*)nx;   // 4096 rows x 256 x 4B = 4 MB, fits nx exactly

  k_prep_w<<<80, 256, 0, stream>>>(W_uvqk, W_o, Wu_t, Wo_t);
  k_ln_in<<<2048, 256, 0, stream>>>(x, ln_in_g, ln_in_b, nx);
  k_gemm_uvqk<<<512, 256, 0, stream>>>(nx, Wu_t, b_uvqk, u, v_tmp, q_t, k_t);
  k_vtrans<<<512, 256, 0, stream>>>(v_tmp, v_t);
  k_attn<<<768, 256, 0, stream>>>(q_t, k_t, v_t, tstamps, lengths, w_pos, w_ts, avP0, avP1);
  k_ln_attn<<<2048, 256, 0, stream>>>(avP0, avP1, u, ln_attn_g, ln_attn_b, a2);
  k_gemm_out<<<512, 256, 0, stream>>>(a2, Wo_t, b_o, x, lengths, out);
}

// Round 10
// 221.537 us; speedup vs baseline: 1.1430x; 1.0702x over previous
//
#include <hip/hip_runtime.h>
#include <stdint.h>

// Problem constants (B,N,D)=(4,2048,256), H=4, DA=DL=64, NUM_BUCKETS=128
#define BB 4
#define NN 2048
#define DD 256
#define HH 4

typedef __attribute__((ext_vector_type(8))) __bf16 bf16x8;
typedef __attribute__((ext_vector_type(4))) float f32x4;
typedef __attribute__((ext_vector_type(8))) unsigned short u16x8;
typedef __attribute__((ext_vector_type(4))) unsigned short u16x4;

__device__ __forceinline__ unsigned short f2bf(float f) {
  union { float f; uint32_t u; } v; v.f = f;
  uint32_t r = v.u + 0x7fffu + ((v.u >> 16) & 1u);   // RNE
  return (unsigned short)(r >> 16);
}
__device__ __forceinline__ float bf2f(unsigned short u) {
  union { uint32_t u; float f; } v; v.u = ((uint32_t)u) << 16; return v.f;
}
__device__ __forceinline__ bf16x8 ld8(const unsigned short* p) {
  return __builtin_bit_cast(bf16x8, *(const u16x8*)p);
}
__device__ __forceinline__ f32x4 mfma16(bf16x8 a, bf16x8 b, f32x4 c) {
  return __builtin_amdgcn_mfma_f32_16x16x32_bf16(a, b, c, 0, 0, 0);
}
__device__ __forceinline__ float silu_f(float x) {
  return x / (1.0f + __expf(-x));
}
// tiles-per-qt prefix: steps(qt)=qt/4+1; off(qt)=(a+1)*(2a+r), a=qt>>2, r=qt&3. off(128)=2112.
__device__ __forceinline__ int bias_off(int qt) {
  int a = qt >> 2, r = qt & 3;
  return (a + 1) * (2 * a + r);
}

// ---------------- K0: weight convert + transpose to bf16 (LDS-tiled) ----------------
__global__ __launch_bounds__(256) void k_prep_w(const float* __restrict__ Wu,
                                                const float* __restrict__ Wo,
                                                unsigned short* __restrict__ Wu_t,
                                                unsigned short* __restrict__ Wo_t) {
  __shared__ float T[64][65];
  int bi = blockIdx.x;
  const float* src; unsigned short* dst; int F, f0, d0;
  if (bi < 64) { src = Wu; dst = Wu_t; F = 1024; f0 = (bi >> 2) * 64; d0 = (bi & 3) * 64; }
  else { int j = bi - 64; src = Wo; dst = Wo_t; F = 256; f0 = (j >> 2) * 64; d0 = (j & 3) * 64; }
  int t = threadIdx.x;
  int li = t >> 4;            // 0..15
  int lj = (t & 15) * 4;      // 0,4,..,60
  #pragma unroll
  for (int it = 0; it < 4; ++it) {
    int d = li + it * 16;
    float4 v = *(const float4*)(src + (size_t)(d0 + d) * F + f0 + lj);
    T[lj + 0][d] = v.x; T[lj + 1][d] = v.y; T[lj + 2][d] = v.z; T[lj + 3][d] = v.w;
  }
  __syncthreads();
  #pragma unroll
  for (int it = 0; it < 4; ++it) {
    int f = li + it * 16;
    u16x4 o;
    o[0] = f2bf(T[f][lj + 0]); o[1] = f2bf(T[f][lj + 1]);
    o[2] = f2bf(T[f][lj + 2]); o[3] = f2bf(T[f][lj + 3]);
    *(u16x4*)(dst + (size_t)(f0 + f) * 256 + d0 + lj) = o;
  }
}

// ---------------- K1: input LayerNorm -> nx (bf16) ----------------
__global__ __launch_bounds__(256) void k_ln_in(const float* __restrict__ x,
                                               const float* __restrict__ g,
                                               const float* __restrict__ be,
                                               unsigned short* __restrict__ nx) {
  int wave = threadIdx.x >> 6, lane = threadIdx.x & 63;
  int row = blockIdx.x * 4 + wave;
  const float4 v = *(const float4*)(x + (size_t)row * DD + lane * 4);
  float s = v.x + v.y + v.z + v.w;
  float sq = v.x * v.x + v.y * v.y + v.z * v.z + v.w * v.w;
  #pragma unroll
  for (int o = 32; o; o >>= 1) { s += __shfl_xor(s, o); sq += __shfl_xor(sq, o); }
  float mean = s * (1.0f / DD);
  float var = sq * (1.0f / DD) - mean * mean;
  float rstd = rsqrtf(var + 1e-5f);
  const float4 gv = *(const float4*)(g + lane * 4);
  const float4 bv = *(const float4*)(be + lane * 4);
  u16x4 o4;
  o4[0] = f2bf((v.x - mean) * rstd * gv.x + bv.x);
  o4[1] = f2bf((v.y - mean) * rstd * gv.y + bv.y);
  o4[2] = f2bf((v.z - mean) * rstd * gv.z + bv.z);
  o4[3] = f2bf((v.w - mean) * rstd * gv.w + bv.w);
  *(u16x4*)(nx + (size_t)row * DD + lane * 4) = o4;
}

// ---------------- K2: GEMM nx(8192x256) @ Wu_t^T -> silu -> scatter u,v,q,k ----
__global__ __launch_bounds__(256) void k_gemm_uvqk(const unsigned short* __restrict__ nx,
                                                   const unsigned short* __restrict__ Wu_t,
                                                   const float* __restrict__ b_uvqk,
                                                   float* __restrict__ u,
                                                   unsigned short* __restrict__ v_tmp,
                                                   unsigned short* __restrict__ q_t,
                                                   unsigned short* __restrict__ k_t) {
  __shared__ unsigned short As[128 * 72];
  __shared__ unsigned short Bs[128 * 72];
  int tid = threadIdx.x, lane = tid & 63, w = tid >> 6;
  int wr = w >> 1, wc = w & 1, c = lane & 15, g = lane >> 4;
  int rblk = blockIdx.x >> 3, cblk = blockIdx.x & 7;
  int R0 = rblk * 128, C0 = cblk * 128;
  f32x4 acc[4][4] = {};
  for (int ks = 0; ks < 4; ++ks) {
    __syncthreads();
    #pragma unroll
    for (int it = 0; it < 4; ++it) {
      int task = tid + it * 256, row = task >> 3, ch = task & 7;
      *(u16x8*)(As + row * 72 + ch * 8) =
          *(const u16x8*)(nx + (size_t)(R0 + row) * 256 + ks * 64 + ch * 8);
      *(u16x8*)(Bs + row * 72 + ch * 8) =
          *(const u16x8*)(Wu_t + (size_t)(C0 + row) * 256 + ks * 64 + ch * 8);
    }
    __syncthreads();
    #pragma unroll
    for (int kk = 0; kk < 2; ++kk) {
      int koff = kk * 32 + g * 8;
      bf16x8 af[4], bfr[4];
      #pragma unroll
      for (int rt = 0; rt < 4; ++rt) af[rt] = ld8(As + (wr * 64 + rt * 16 + c) * 72 + koff);
      #pragma unroll
      for (int ct = 0; ct < 4; ++ct) bfr[ct] = ld8(Bs + (wc * 64 + ct * 16 + c) * 72 + koff);
      #pragma unroll
      for (int rt = 0; rt < 4; ++rt)
        #pragma unroll
        for (int ct = 0; ct < 4; ++ct)
          acc[rt][ct] = mfma16(af[rt], bfr[ct], acc[rt][ct]);
    }
  }
  #pragma unroll
  for (int rt = 0; rt < 4; ++rt) {
    #pragma unroll
    for (int ct = 0; ct < 4; ++ct) {
      int F = C0 + wc * 64 + ct * 16 + c;
      float bb = b_uvqk[F];
      #pragma unroll
      for (int rr = 0; rr < 4; ++rr) {
        int R = R0 + wr * 64 + rt * 16 + g * 4 + rr;
        float pre = acc[rt][ct][rr] + bb;
        float sv = silu_f(pre);
        int b = R >> 11, n = R & 2047;
        if (F < 256) {
          u[(size_t)R * 256 + F] = sv;
        } else if (F < 512) {
          v_tmp[(size_t)R * 256 + (F - 256)] = f2bf(sv);
        } else if (F < 768) {
          int h = (F - 512) >> 6, d = (F - 512) & 63;
          q_t[((size_t)((b << 2) + h) * 2048 + n) * 64 + d] = f2bf(sv);
        } else {
          int h = (F - 768) >> 6, d = (F - 768) & 63;
          k_t[((size_t)((b << 2) + h) * 2048 + n) * 64 + d] = f2bf(sv);
        }
      }
    }
  }
}

// ---------------- K2b: transpose v_tmp (B,N,H,64) -> v_t (B,H,64,N) ----------------
__global__ __launch_bounds__(256) void k_vtrans(const unsigned short* __restrict__ v_tmp,
                                                unsigned short* __restrict__ v_t) {
  __shared__ unsigned short T[64 * 72];
  int bi = blockIdx.x;
  int nch = bi & 31, h = (bi >> 5) & 3, b = bi >> 7;
  int n0 = nch * 64;
  int tid = threadIdx.x;
  #pragma unroll
  for (int it = 0; it < 2; ++it) {
    int task = tid + it * 256;
    int i = task >> 3, ch = task & 7;
    *(u16x8*)(T + i * 72 + ch * 8) =
        *(const u16x8*)(v_tmp + ((size_t)(b * 2048 + n0 + i)) * 256 + h * 64 + ch * 8);
  }
  __syncthreads();
  #pragma unroll
  for (int it = 0; it < 2; ++it) {
    int task = tid + it * 256;
    int d = task >> 3, ch = task & 7;
    u16x8 ov;
    #pragma unroll
    for (int uu = 0; uu < 8; ++uu) ov[uu] = T[(ch * 8 + uu) * 72 + d];
    *(u16x8*)(v_t + ((size_t)((b * 4 + h) * 64 + d)) * 2048 + n0 + ch * 8) = ov;
  }
}

// ---------------- K2c: bias tile precompute ----------------
// For b, qt, mc (mc <= qt>>2, mc*64 < Lb): tile = b*2112 + off(qt) + mc, 1024 bf16.
// Layout matches attention's C-fragment consumption: element ei = l*16 + idx,
// l = lane (0..63), idx = mt*4 + rr; value = bias(n = qt*16 + (l>>4)*4 + rr,
// m = mc*64 + mt*16 + (l&15)).
// Thread t writes ei = t*4 + j (j=0..3): l = t>>2, mt = t&3, rr = j -> one u16x4 store.
__global__ __launch_bounds__(256) void k_bias(const int* __restrict__ ts_raw,
                                              const int* __restrict__ lens_raw,
                                              const float* __restrict__ w_pos,
                                              const float* __restrict__ w_ts,
                                              unsigned short* __restrict__ bias_t) {
  int bi = blockIdx.x;              // grid 4*128*32 = 16384
  int b = bi >> 12, qt = (bi >> 5) & 127, mc = bi & 31;
  if (mc > (qt >> 2)) return;
  int stride = (lens_raw[1] == 0 && lens_raw[3] == 0) ? 2 : 1;
  int Lb = lens_raw[b * stride];
  if (mc * 64 >= Lb) return;        // never read (kv loop stops at Lb); lengths constant per session
  const int* tsb = ts_raw + (size_t)b * 2048 * stride;
  int t = threadIdx.x;
  int l = t >> 2, mt = t & 3;
  int m = mc * 64 + mt * 16 + (l & 15);
  int nbase = qt * 16 + ((l >> 4) << 2);
  int tm = tsb[m * stride];
  size_t tile = (size_t)(b * 2112 + bias_off(qt) + mc);
  u16x4 o;
  #pragma unroll
  for (int j = 0; j < 4; ++j) {
    int n = nbase + j;
    int dtv = tsb[n * stride] - tm;
    float ad = fmaxf(fabsf((float)dtv), 1.0f);
    int bk = (int)(__log2f(ad) * 2.3028145f);   // log(x)/0.301 == log2(x)*(ln2/0.301)
    bk = bk > 128 ? 128 : bk;
    o[j] = f2bf(w_pos[n - m + 2047] + w_ts[bk]);
  }
  *(u16x4*)(bias_t + tile * 1024 + t * 4) = o;
}

// ---------------- K3: fused attention, barrier-free, split-K=2, precomputed bias ----
// silu(qk+bias)/N with causal+len mask; NO softmax (pure running sum -> no rescale).
// Block = 4 waves = 4 heads, one (b, 16-row q-tile, KV-chunk). Bias tile loaded as two
// 16B coalesced reads per step (C-fragment order). No __syncthreads in the KV loop;
// P goes through a per-wave LDS tile (same-wave in-order LDS).
__global__ __launch_bounds__(256) void k_attn(const unsigned short* __restrict__ q_t,
                                              const unsigned short* __restrict__ k_t,
                                              const unsigned short* __restrict__ v_t,
                                              const unsigned short* __restrict__ bias_t,
                                              const int* __restrict__ lens_raw,
                                              float* __restrict__ avP0,
                                              float* __restrict__ avP1) {
  __shared__ unsigned short P_s[4][16 * 72];
  int tid = threadIdx.x, lane = tid & 63, h = tid >> 6;
  int c = lane & 15, g = lane >> 4;
  int bi = blockIdx.x;
  int b, qt, chunk;
  if (bi < 512) { chunk = 0; b = bi & 3; qt = 127 - (bi >> 2); }
  else { chunk = 1; int j = bi - 512; b = j & 3; qt = 127 - (j >> 2); }   // qt in [64,127]
  int n0 = qt * 16;
  int stride = (lens_raw[1] == 0 && lens_raw[3] == 0) ? 2 : 1;
  int Lb = lens_raw[b * stride];
  const unsigned short* qp = q_t + (size_t)(b * 4 + h) * 2048 * 64;
  const unsigned short* kp = k_t + (size_t)(b * 4 + h) * 2048 * 64;
  const unsigned short* vp = v_t + (size_t)(b * 4 + h) * 64 * 2048;
  const unsigned short* btile = bias_t + ((size_t)(b * 2112 + bias_off(qt))) * 1024 + lane * 16;

  int m_end = min(n0 + 16, Lb);
  int kv_lo = chunk ? 1024 : 0;
  int kv_hi = chunk ? m_end : min(m_end, 1024);

  bf16x8 qf0 = ld8(qp + (size_t)(n0 + c) * 64 + g * 8);
  bf16x8 qf1 = ld8(qp + (size_t)(n0 + c) * 64 + 32 + g * 8);
  unsigned short* Pw = &P_s[h][0];
  f32x4 av[4] = {};

  for (int m0 = kv_lo; m0 < kv_hi; m0 += 64) {
    // bias fragment for this step: 16 bf16 per lane, contiguous (C-frag order)
    const unsigned short* bp = btile + (size_t)(m0 >> 6) * 1024;
    u16x8 bt0 = *(const u16x8*)bp;
    u16x8 bt1 = *(const u16x8*)(bp + 8);
    // qk^T: 16x64 per wave
    f32x4 s[4] = {};
    #pragma unroll
    for (int mt = 0; mt < 4; ++mt) {
      const unsigned short* kr = kp + (size_t)(m0 + mt * 16 + c) * 64 + g * 8;
      s[mt] = mfma16(qf0, ld8(kr), s[mt]);
      s[mt] = mfma16(qf1, ld8(kr + 32), s[mt]);
    }
    // bias + silu + mask, in registers at C-frag positions -> bf16 -> per-wave LDS
    #pragma unroll
    for (int mt = 0; mt < 4; ++mt) {
      int m = m0 + mt * 16 + c;
      #pragma unroll
      for (int rr = 0; rr < 4; ++rr) {
        int n = n0 + g * 4 + rr;
        int idx = mt * 4 + rr;
        unsigned short ub = idx < 8 ? bt0[idx] : bt1[idx - 8];
        float sv = s[mt][rr] + bf2f(ub);
        float p = (m <= n && m < Lb) ? silu_f(sv) * (1.0f / 2048.0f) : 0.0f;
        Pw[(g * 4 + rr) * 72 + mt * 16 + c] = f2bf(p);
      }
    }
    // PV: av(16x64) += P(16x64) @ V(64x64); A-frag via same-wave LDS round-trip
    #pragma unroll
    for (int kk = 0; kk < 2; ++kk) {
      bf16x8 pa = ld8(Pw + c * 72 + kk * 32 + g * 8);
      #pragma unroll
      for (int dt = 0; dt < 4; ++dt) {
        bf16x8 vf = ld8(vp + (size_t)(dt * 16 + c) * 2048 + m0 + kk * 32 + g * 8);
        av[dt] = mfma16(pa, vf, av[dt]);
      }
    }
  }

  if (chunk == 0) {
    #pragma unroll
    for (int dt = 0; dt < 4; ++dt)
      #pragma unroll
      for (int rr = 0; rr < 4; ++rr) {
        int n = n0 + g * 4 + rr;
        avP0[((size_t)(b * 2048 + n)) * 256 + h * 64 + dt * 16 + c] = av[dt][rr];
      }
  } else {
    #pragma unroll
    for (int dt = 0; dt < 4; ++dt)
      #pragma unroll
      for (int rr = 0; rr < 4; ++rr) {
        int n = n0 + g * 4 + rr;
        avP1[((size_t)(b * 1024 + (n - 1024))) * 256 + h * 64 + dt * 16 + c] = av[dt][rr];
      }
  }
}

// ---------------- K4: LayerNorm(avP0+avP1) * u -> a2 (bf16) ----------------
__global__ __launch_bounds__(256) void k_ln_attn(const float* __restrict__ avP0,
                                                 const float* __restrict__ avP1,
                                                 const float* __restrict__ u,
                                                 const float* __restrict__ g,
                                                 const float* __restrict__ be,
                                                 unsigned short* __restrict__ a2) {
  int wave = threadIdx.x >> 6, lane = threadIdx.x & 63;
  int row = blockIdx.x * 4 + wave;
  int n = row & 2047, b = row >> 11;
  float4 v = *(const float4*)(avP0 + (size_t)row * DD + lane * 4);
  if (n >= 1024) {
    const float4 w = *(const float4*)(avP1 + ((size_t)(b * 1024 + (n - 1024))) * DD + lane * 4);
    v.x += w.x; v.y += w.y; v.z += w.z; v.w += w.w;
  }
  float s = v.x + v.y + v.z + v.w;
  float sq = v.x * v.x + v.y * v.y + v.z * v.z + v.w * v.w;
  #pragma unroll
  for (int o = 32; o; o >>= 1) { s += __shfl_xor(s, o); sq += __shfl_xor(sq, o); }
  float mean = s * (1.0f / DD);
  float var = sq * (1.0f / DD) - mean * mean;
  float rstd = rsqrtf(var + 1e-5f);
  const float4 gv = *(const float4*)(g + lane * 4);
  const float4 bv = *(const float4*)(be + lane * 4);
  const float4 uv = *(const float4*)(u + (size_t)row * DD + lane * 4);
  u16x4 o4;
  o4[0] = f2bf(((v.x - mean) * rstd * gv.x + bv.x) * uv.x);
  o4[1] = f2bf(((v.y - mean) * rstd * gv.y + bv.y) * uv.y);
  o4[2] = f2bf(((v.z - mean) * rstd * gv.z + bv.z) * uv.z);
  o4[3] = f2bf(((v.w - mean) * rstd * gv.w + bv.w) * uv.w);
  *(u16x4*)(a2 + (size_t)row * DD + lane * 4) = o4;
}

// ---------------- K5: out GEMM a2(8192x256) @ Wo_t^T + b_o + x, row-mask ---------
__global__ __launch_bounds__(256) void k_gemm_out(const unsigned short* __restrict__ a2,
                                                  const unsigned short* __restrict__ Wo_t,
                                                  const float* __restrict__ b_o,
                                                  const float* __restrict__ x,
                                                  const int* __restrict__ lens_raw,
                                                  float* __restrict__ out) {
  __shared__ unsigned short As[64 * 72];
  __shared__ unsigned short Bs[64 * 72];
  int tid = threadIdx.x, lane = tid & 63, w = tid >> 6;
  int wr = w >> 1, wc = w & 1, c = lane & 15, g = lane >> 4;
  int rblk = blockIdx.x >> 2, cblk = blockIdx.x & 3;
  int R0 = rblk * 64, C0 = cblk * 64;
  int stride = (lens_raw[1] == 0 && lens_raw[3] == 0) ? 2 : 1;
  f32x4 acc[2][2] = {};
  for (int ks = 0; ks < 4; ++ks) {
    __syncthreads();
    #pragma unroll
    for (int it = 0; it < 2; ++it) {
      int task = tid + it * 256, row = task >> 3, ch = task & 7;
      *(u16x8*)(As + row * 72 + ch * 8) =
          *(const u16x8*)(a2 + (size_t)(R0 + row) * 256 + ks * 64 + ch * 8);
      *(u16x8*)(Bs + row * 72 + ch * 8) =
          *(const u16x8*)(Wo_t + (size_t)(C0 + row) * 256 + ks * 64 + ch * 8);
    }
    __syncthreads();
    #pragma unroll
    for (int kk = 0; kk < 2; ++kk) {
      int koff = kk * 32 + g * 8;
      bf16x8 af[2], bfr[2];
      #pragma unroll
      for (int rt = 0; rt < 2; ++rt) af[rt] = ld8(As + (wr * 32 + rt * 16 + c) * 72 + koff);
      #pragma unroll
      for (int ct = 0; ct < 2; ++ct) bfr[ct] = ld8(Bs + (wc * 32 + ct * 16 + c) * 72 + koff);
      #pragma unroll
      for (int rt = 0; rt < 2; ++rt)
        #pragma unroll
        for (int ct = 0; ct < 2; ++ct)
          acc[rt][ct] = mfma16(af[rt], bfr[ct], acc[rt][ct]);
    }
  }
  #pragma unroll
  for (int rt = 0; rt < 2; ++rt) {
    #pragma unroll
    for (int ct = 0; ct < 2; ++ct) {
      int F = C0 + wc * 32 + ct * 16 + c;
      float bo = b_o[F];
      #pragma unroll
      for (int rr = 0; rr < 4; ++rr) {
        int R = R0 + wr * 32 + rt * 16 + g * 4 + rr;
        int b = R >> 11, n = R & 2047;
        int Lb = lens_raw[b * stride];
        float val = acc[rt][ct][rr] + bo + x[(size_t)R * 256 + F];
        out[(size_t)R * 256 + F] = (n < Lb) ? val : 0.0f;
      }
    }
  }
}

// ---------------- launch ----------------
extern "C" void kernel_launch(void* const* d_in, const int* in_sizes, int n_in,
                              void* d_out, int out_size, void* d_ws, size_t ws_size,
                              hipStream_t stream) {
  const float* x        = (const float*)d_in[0];
  const float* W_uvqk   = (const float*)d_in[1];
  const float* b_uvqk   = (const float*)d_in[2];
  const float* W_o      = (const float*)d_in[3];
  const float* b_o      = (const float*)d_in[4];
  const float* ln_in_g  = (const float*)d_in[5];
  const float* ln_in_b  = (const float*)d_in[6];
  const float* ln_attn_g= (const float*)d_in[7];
  const float* ln_attn_b= (const float*)d_in[8];
  const float* w_pos    = (const float*)d_in[9];
  const float* w_ts     = (const float*)d_in[10];
  const int*   lengths  = (const int*)d_in[11];
  const int*   tstamps  = (const int*)d_in[12];
  float* out = (float*)d_out;

  char* ws = (char*)d_ws;
  size_t off = 0;
  auto alloc = [&](size_t bytes) -> void* {
    void* p = ws + off;
    off += (bytes + 255) & ~(size_t)255;
    return p;
  };
  unsigned short* Wu_t  = (unsigned short*)alloc(1024 * 256 * 2);
  unsigned short* Wo_t  = (unsigned short*)alloc(256 * 256 * 2);
  unsigned short* nx    = (unsigned short*)alloc((size_t)8192 * 256 * 2);  // reused as avP1 after gemm_uvqk
  float*          u     = (float*)alloc((size_t)8192 * 256 * 4);
  unsigned short* v_t   = (unsigned short*)alloc((size_t)8192 * 256 * 2);
  unsigned short* q_t   = (unsigned short*)alloc((size_t)8192 * 256 * 2);
  unsigned short* k_t   = (unsigned short*)alloc((size_t)8192 * 256 * 2);
  float*          avP0  = (float*)alloc((size_t)8192 * 256 * 4);
  unsigned short* a2    = (unsigned short*)alloc((size_t)8192 * 256 * 2);
  // v_tmp is dead after k_vtrans; bias tiles (written later) overlay it.
  unsigned short* v_tmp = (unsigned short*)alloc((size_t)8192 * 256 * 2);
  unsigned short* bias_t = (unsigned short*)v_tmp;   // 4*2112*1024*2 B = 16.5 MB (extends past v_tmp)
  (void)alloc((size_t)4 * 2112 * 1024 * 2 - (size_t)8192 * 256 * 2);  // reserve the extension
  float*          avP1  = (float*)nx;   // 4096 rows x 256 x 4B = 4 MB, fits nx exactly

  k_prep_w<<<80, 256, 0, stream>>>(W_uvqk, W_o, Wu_t, Wo_t);
  k_ln_in<<<2048, 256, 0, stream>>>(x, ln_in_g, ln_in_b, nx);
  k_gemm_uvqk<<<512, 256, 0, stream>>>(nx, Wu_t, b_uvqk, u, v_tmp, q_t, k_t);
  k_vtrans<<<512, 256, 0, stream>>>(v_tmp, v_t);
  k_bias<<<16384, 256, 0, stream>>>(tstamps, lengths, w_pos, w_ts, bias_t);
  k_attn<<<768, 256, 0, stream>>>(q_t, k_t, v_t, bias_t, lengths, avP0, avP1);
  k_ln_attn<<<2048, 256, 0, stream>>>(avP0, avP1, u, ln_attn_g, ln_attn_b, a2);
  k_gemm_out<<<512, 256, 0, stream>>>(a2, Wo_t, b_o, x, lengths, out);
}

// Round 13
// 216.449 us; speedup vs baseline: 1.1699x; 1.0235x over previous
//
#include <hip/hip_runtime.h>
#include <stdint.h>

// Problem constants (B,N,D)=(4,2048,256), H=4, DA=DL=64, NUM_BUCKETS=128
#define BB 4
#define NN 2048
#define DD 256
#define HH 4

typedef __attribute__((ext_vector_type(8))) __bf16 bf16x8;
typedef __attribute__((ext_vector_type(4))) float f32x4;
typedef __attribute__((ext_vector_type(8))) unsigned short u16x8;
typedef __attribute__((ext_vector_type(4))) unsigned short u16x4;

__device__ __forceinline__ unsigned short f2bf(float f) {
  union { float f; uint32_t u; } v; v.f = f;
  uint32_t r = v.u + 0x7fffu + ((v.u >> 16) & 1u);   // RNE
  return (unsigned short)(r >> 16);
}
__device__ __forceinline__ float bf2f(unsigned short u) {
  union { uint32_t u; float f; } v; v.u = ((uint32_t)u) << 16; return v.f;
}
__device__ __forceinline__ bf16x8 ld8(const unsigned short* p) {
  return __builtin_bit_cast(bf16x8, *(const u16x8*)p);
}
__device__ __forceinline__ f32x4 mfma16(bf16x8 a, bf16x8 b, f32x4 c) {
  return __builtin_amdgcn_mfma_f32_16x16x32_bf16(a, b, c, 0, 0, 0);
}
__device__ __forceinline__ float silu_f(float x) {
  return x / (1.0f + __expf(-x));
}
// tiles-per-qt prefix: steps(qt)=qt/4+1; off(qt)=(a+1)*(2a+r), a=qt>>2, r=qt&3. off(128)=2112.
__device__ __forceinline__ int bias_off(int qt) {
  int a = qt >> 2, r = qt & 3;
  return (a + 1) * (2 * a + r);
}

// ---------------- K0: weight convert + transpose to bf16 (LDS-tiled) ----------------
__global__ __launch_bounds__(256) void k_prep_w(const float* __restrict__ Wu,
                                                const float* __restrict__ Wo,
                                                unsigned short* __restrict__ Wu_t,
                                                unsigned short* __restrict__ Wo_t) {
  __shared__ float T[64][65];
  int bi = blockIdx.x;
  const float* src; unsigned short* dst; int F, f0, d0;
  if (bi < 64) { src = Wu; dst = Wu_t; F = 1024; f0 = (bi >> 2) * 64; d0 = (bi & 3) * 64; }
  else { int j = bi - 64; src = Wo; dst = Wo_t; F = 256; f0 = (j >> 2) * 64; d0 = (j & 3) * 64; }
  int t = threadIdx.x;
  int li = t >> 4;            // 0..15
  int lj = (t & 15) * 4;      // 0,4,..,60
  #pragma unroll
  for (int it = 0; it < 4; ++it) {
    int d = li + it * 16;
    float4 v = *(const float4*)(src + (size_t)(d0 + d) * F + f0 + lj);
    T[lj + 0][d] = v.x; T[lj + 1][d] = v.y; T[lj + 2][d] = v.z; T[lj + 3][d] = v.w;
  }
  __syncthreads();
  #pragma unroll
  for (int it = 0; it < 4; ++it) {
    int f = li + it * 16;
    u16x4 o;
    o[0] = f2bf(T[f][lj + 0]); o[1] = f2bf(T[f][lj + 1]);
    o[2] = f2bf(T[f][lj + 2]); o[3] = f2bf(T[f][lj + 3]);
    *(u16x4*)(dst + (size_t)(f0 + f) * 256 + d0 + lj) = o;
  }
}

// ---------------- K0b: zero the attention accumulator ----------------
__global__ __launch_bounds__(256) void k_zero(float* __restrict__ p) {
  size_t i = ((size_t)blockIdx.x * 256 + threadIdx.x) * 4;
  float4 z = {0.0f, 0.0f, 0.0f, 0.0f};
  *(float4*)(p + i) = z;
}

// ---------------- K1: input LayerNorm -> nx (bf16) ----------------
__global__ __launch_bounds__(256) void k_ln_in(const float* __restrict__ x,
                                               const float* __restrict__ g,
                                               const float* __restrict__ be,
                                               unsigned short* __restrict__ nx) {
  int wave = threadIdx.x >> 6, lane = threadIdx.x & 63;
  int row = blockIdx.x * 4 + wave;
  const float4 v = *(const float4*)(x + (size_t)row * DD + lane * 4);
  float s = v.x + v.y + v.z + v.w;
  float sq = v.x * v.x + v.y * v.y + v.z * v.z + v.w * v.w;
  #pragma unroll
  for (int o = 32; o; o >>= 1) { s += __shfl_xor(s, o); sq += __shfl_xor(sq, o); }
  float mean = s * (1.0f / DD);
  float var = sq * (1.0f / DD) - mean * mean;
  float rstd = rsqrtf(var + 1e-5f);
  const float4 gv = *(const float4*)(g + lane * 4);
  const float4 bv = *(const float4*)(be + lane * 4);
  u16x4 o4;
  o4[0] = f2bf((v.x - mean) * rstd * gv.x + bv.x);
  o4[1] = f2bf((v.y - mean) * rstd * gv.y + bv.y);
  o4[2] = f2bf((v.z - mean) * rstd * gv.z + bv.z);
  o4[3] = f2bf((v.w - mean) * rstd * gv.w + bv.w);
  *(u16x4*)(nx + (size_t)row * DD + lane * 4) = o4;
}

// ---------------- K2: GEMM nx(8192x256) @ Wu_t^T -> silu -> scatter u,v,q,k ----
__global__ __launch_bounds__(256) void k_gemm_uvqk(const unsigned short* __restrict__ nx,
                                                   const unsigned short* __restrict__ Wu_t,
                                                   const float* __restrict__ b_uvqk,
                                                   float* __restrict__ u,
                                                   unsigned short* __restrict__ v_tmp,
                                                   unsigned short* __restrict__ q_t,
                                                   unsigned short* __restrict__ k_t) {
  __shared__ unsigned short As[128 * 72];
  __shared__ unsigned short Bs[128 * 72];
  int tid = threadIdx.x, lane = tid & 63, w = tid >> 6;
  int wr = w >> 1, wc = w & 1, c = lane & 15, g = lane >> 4;
  int rblk = blockIdx.x >> 3, cblk = blockIdx.x & 7;
  int R0 = rblk * 128, C0 = cblk * 128;
  f32x4 acc[4][4] = {};
  for (int ks = 0; ks < 4; ++ks) {
    __syncthreads();
    #pragma unroll
    for (int it = 0; it < 4; ++it) {
      int task = tid + it * 256, row = task >> 3, ch = task & 7;
      *(u16x8*)(As + row * 72 + ch * 8) =
          *(const u16x8*)(nx + (size_t)(R0 + row) * 256 + ks * 64 + ch * 8);
      *(u16x8*)(Bs + row * 72 + ch * 8) =
          *(const u16x8*)(Wu_t + (size_t)(C0 + row) * 256 + ks * 64 + ch * 8);
    }
    __syncthreads();
    #pragma unroll
    for (int kk = 0; kk < 2; ++kk) {
      int koff = kk * 32 + g * 8;
      bf16x8 af[4], bfr[4];
      #pragma unroll
      for (int rt = 0; rt < 4; ++rt) af[rt] = ld8(As + (wr * 64 + rt * 16 + c) * 72 + koff);
      #pragma unroll
      for (int ct = 0; ct < 4; ++ct) bfr[ct] = ld8(Bs + (wc * 64 + ct * 16 + c) * 72 + koff);
      #pragma unroll
      for (int rt = 0; rt < 4; ++rt)
        #pragma unroll
        for (int ct = 0; ct < 4; ++ct)
          acc[rt][ct] = mfma16(af[rt], bfr[ct], acc[rt][ct]);
    }
  }
  #pragma unroll
  for (int rt = 0; rt < 4; ++rt) {
    #pragma unroll
    for (int ct = 0; ct < 4; ++ct) {
      int F = C0 + wc * 64 + ct * 16 + c;
      float bb = b_uvqk[F];
      #pragma unroll
      for (int rr = 0; rr < 4; ++rr) {
        int R = R0 + wr * 64 + rt * 16 + g * 4 + rr;
        float pre = acc[rt][ct][rr] + bb;
        float sv = silu_f(pre);
        int b = R >> 11, n = R & 2047;
        if (F < 256) {
          u[(size_t)R * 256 + F] = sv;
        } else if (F < 512) {
          v_tmp[(size_t)R * 256 + (F - 256)] = f2bf(sv);
        } else if (F < 768) {
          int h = (F - 512) >> 6, d = (F - 512) & 63;
          q_t[((size_t)((b << 2) + h) * 2048 + n) * 64 + d] = f2bf(sv);
        } else {
          int h = (F - 768) >> 6, d = (F - 768) & 63;
          k_t[((size_t)((b << 2) + h) * 2048 + n) * 64 + d] = f2bf(sv);
        }
      }
    }
  }
}

// ---------------- K2b: transpose v_tmp (B,N,H,64) -> v_t (B,H,64,N) ----------------
__global__ __launch_bounds__(256) void k_vtrans(const unsigned short* __restrict__ v_tmp,
                                                unsigned short* __restrict__ v_t) {
  __shared__ unsigned short T[64 * 72];
  int bi = blockIdx.x;
  int nch = bi & 31, h = (bi >> 5) & 3, b = bi >> 7;
  int n0 = nch * 64;
  int tid = threadIdx.x;
  #pragma unroll
  for (int it = 0; it < 2; ++it) {
    int task = tid + it * 256;
    int i = task >> 3, ch = task & 7;
    *(u16x8*)(T + i * 72 + ch * 8) =
        *(const u16x8*)(v_tmp + ((size_t)(b * 2048 + n0 + i)) * 256 + h * 64 + ch * 8);
  }
  __syncthreads();
  #pragma unroll
  for (int it = 0; it < 2; ++it) {
    int task = tid + it * 256;
    int d = task >> 3, ch = task & 7;
    u16x8 ov;
    #pragma unroll
    for (int uu = 0; uu < 8; ++uu) ov[uu] = T[(ch * 8 + uu) * 72 + d];
    *(u16x8*)(v_t + ((size_t)((b * 4 + h) * 64 + d)) * 2048 + n0 + ch * 8) = ov;
  }
}

// ---------------- K2c: bias tile precompute ----------------
// For b, qt, mc (mc <= qt>>2, mc*64 < Lb): tile = b*2112 + off(qt) + mc, 1024 bf16.
// Layout matches attention's C-fragment consumption: element ei = l*16 + idx,
// l = lane (0..63), idx = mt*4 + rr; value = bias(n = qt*16 + (l>>4)*4 + rr,
// m = mc*64 + mt*16 + (l&15)).
__global__ __launch_bounds__(256) void k_bias(const int* __restrict__ ts_raw,
                                              const int* __restrict__ lens_raw,
                                              const float* __restrict__ w_pos,
                                              const float* __restrict__ w_ts,
                                              unsigned short* __restrict__ bias_t) {
  int bi = blockIdx.x;              // grid 4*128*32 = 16384
  int b = bi >> 12, qt = (bi >> 5) & 127, mc = bi & 31;
  if (mc > (qt >> 2)) return;
  int stride = (lens_raw[1] == 0 && lens_raw[3] == 0) ? 2 : 1;
  int Lb = lens_raw[b * stride];
  if (mc * 64 >= Lb) return;        // never read (kv loop stops at Lb)
  const int* tsb = ts_raw + (size_t)b * 2048 * stride;
  int t = threadIdx.x;
  int l = t >> 2, mt = t & 3;
  int m = mc * 64 + mt * 16 + (l & 15);
  int nbase = qt * 16 + ((l >> 4) << 2);
  int tm = tsb[m * stride];
  size_t tile = (size_t)(b * 2112 + bias_off(qt) + mc);
  u16x4 o;
  #pragma unroll
  for (int j = 0; j < 4; ++j) {
    int n = nbase + j;
    int dtv = tsb[n * stride] - tm;
    float ad = fmaxf(fabsf((float)dtv), 1.0f);
    int bk = (int)(__log2f(ad) * 2.3028145f);   // log(x)/0.301 == log2(x)*(ln2/0.301)
    bk = bk > 128 ? 128 : bk;
    o[j] = f2bf(w_pos[n - m + 2047] + w_ts[bk]);
  }
  *(u16x4*)(bias_t + tile * 1024 + t * 4) = o;
}

// ---------------- K3: fused attention, uniform split-K=8, atomic accumulate ----------
// silu(qk+bias)/N with causal+len mask; NO softmax (pure running sum -> atomics OK).
// Block = 4 waves = 4 heads, one (b, 16-row q-tile, 256-row KV chunk) -> <=4 steps.
// Grid 4096 = 8 ck x 128 qt x 4 b; empty chunks exit immediately. Partials are
// atomicAdd'ed into zeroed avF (device-scope, cross-XCD safe).
__global__ __launch_bounds__(256) void k_attn(const unsigned short* __restrict__ q_t,
                                              const unsigned short* __restrict__ k_t,
                                              const unsigned short* __restrict__ v_t,
                                              const unsigned short* __restrict__ bias_t,
                                              const int* __restrict__ lens_raw,
                                              float* __restrict__ avF) {
  __shared__ unsigned short P_s[4][16 * 72];
  int tid = threadIdx.x, lane = tid & 63, h = tid >> 6;
  int c = lane & 15, g = lane >> 4;
  int bi = blockIdx.x;
  int b = bi & 3, qt = 127 - ((bi >> 2) & 127), ck = bi >> 9;
  int n0 = qt * 16;
  int stride = (lens_raw[1] == 0 && lens_raw[3] == 0) ? 2 : 1;
  int Lb = lens_raw[b * stride];
  int m_end = min(n0 + 16, Lb);
  int kv_lo = ck * 256;
  if (kv_lo >= m_end) return;
  int kv_hi = min(kv_lo + 256, m_end);

  const unsigned short* qp = q_t + (size_t)(b * 4 + h) * 2048 * 64;
  const unsigned short* kp = k_t + (size_t)(b * 4 + h) * 2048 * 64;
  const unsigned short* vp = v_t + (size_t)(b * 4 + h) * 64 * 2048;
  const unsigned short* btile = bias_t + ((size_t)(b * 2112 + bias_off(qt))) * 1024 + lane * 16;

  bf16x8 qf0 = ld8(qp + (size_t)(n0 + c) * 64 + g * 8);
  bf16x8 qf1 = ld8(qp + (size_t)(n0 + c) * 64 + 32 + g * 8);
  unsigned short* Pw = &P_s[h][0];
  f32x4 av[4] = {};

  for (int m0 = kv_lo; m0 < kv_hi; m0 += 64) {
    // bias fragment for this step: 16 bf16 per lane, contiguous (C-frag order)
    const unsigned short* bp = btile + (size_t)(m0 >> 6) * 1024;
    u16x8 bt0 = *(const u16x8*)bp;
    u16x8 bt1 = *(const u16x8*)(bp + 8);
    // qk^T: 16x64 per wave
    f32x4 s[4] = {};
    #pragma unroll
    for (int mt = 0; mt < 4; ++mt) {
      const unsigned short* kr = kp + (size_t)(m0 + mt * 16 + c) * 64 + g * 8;
      s[mt] = mfma16(qf0, ld8(kr), s[mt]);
      s[mt] = mfma16(qf1, ld8(kr + 32), s[mt]);
    }
    // bias + silu + mask, in registers at C-frag positions -> bf16 -> per-wave LDS
    #pragma unroll
    for (int mt = 0; mt < 4; ++mt) {
      int m = m0 + mt * 16 + c;
      #pragma unroll
      for (int rr = 0; rr < 4; ++rr) {
        int n = n0 + g * 4 + rr;
        int idx = mt * 4 + rr;
        unsigned short ub = idx < 8 ? bt0[idx] : bt1[idx - 8];
        float sv = s[mt][rr] + bf2f(ub);
        float p = (m <= n && m < Lb) ? silu_f(sv) * (1.0f / 2048.0f) : 0.0f;
        Pw[(g * 4 + rr) * 72 + mt * 16 + c] = f2bf(p);
      }
    }
    // PV: av(16x64) += P(16x64) @ V(64x64); A-frag via same-wave LDS round-trip
    #pragma unroll
    for (int kk = 0; kk < 2; ++kk) {
      bf16x8 pa = ld8(Pw + c * 72 + kk * 32 + g * 8);
      #pragma unroll
      for (int dt = 0; dt < 4; ++dt) {
        bf16x8 vf = ld8(vp + (size_t)(dt * 16 + c) * 2048 + m0 + kk * 32 + g * 8);
        av[dt] = mfma16(pa, vf, av[dt]);
      }
    }
  }

  #pragma unroll
  for (int dt = 0; dt < 4; ++dt)
    #pragma unroll
    for (int rr = 0; rr < 4; ++rr) {
      int n = n0 + g * 4 + rr;
      atomicAdd(avF + ((size_t)(b * 2048 + n)) * 256 + h * 64 + dt * 16 + c, av[dt][rr]);
    }
}

// ---------------- K4: LayerNorm(avF) * u -> a2 (bf16) ----------------
__global__ __launch_bounds__(256) void k_ln_attn(const float* __restrict__ avF,
                                                 const float* __restrict__ u,
                                                 const float* __restrict__ g,
                                                 const float* __restrict__ be,
                                                 unsigned short* __restrict__ a2) {
  int wave = threadIdx.x >> 6, lane = threadIdx.x & 63;
  int row = blockIdx.x * 4 + wave;
  const float4 v = *(const float4*)(avF + (size_t)row * DD + lane * 4);
  float s = v.x + v.y + v.z + v.w;
  float sq = v.x * v.x + v.y * v.y + v.z * v.z + v.w * v.w;
  #pragma unroll
  for (int o = 32; o; o >>= 1) { s += __shfl_xor(s, o); sq += __shfl_xor(sq, o); }
  float mean = s * (1.0f / DD);
  float var = sq * (1.0f / DD) - mean * mean;
  float rstd = rsqrtf(var + 1e-5f);
  const float4 gv = *(const float4*)(g + lane * 4);
  const float4 bv = *(const float4*)(be + lane * 4);
  const float4 uv = *(const float4*)(u + (size_t)row * DD + lane * 4);
  u16x4 o4;
  o4[0] = f2bf(((v.x - mean) * rstd * gv.x + bv.x) * uv.x);
  o4[1] = f2bf(((v.y - mean) * rstd * gv.y + bv.y) * uv.y);
  o4[2] = f2bf(((v.z - mean) * rstd * gv.z + bv.z) * uv.z);
  o4[3] = f2bf(((v.w - mean) * rstd * gv.w + bv.w) * uv.w);
  *(u16x4*)(a2 + (size_t)row * DD + lane * 4) = o4;
}

// ---------------- K5: out GEMM a2(8192x256) @ Wo_t^T + b_o + x, row-mask ---------
__global__ __launch_bounds__(256) void k_gemm_out(const unsigned short* __restrict__ a2,
                                                  const unsigned short* __restrict__ Wo_t,
                                                  const float* __restrict__ b_o,
                                                  const float* __restrict__ x,
                                                  const int* __restrict__ lens_raw,
                                                  float* __restrict__ out) {
  __shared__ unsigned short As[64 * 72];
  __shared__ unsigned short Bs[64 * 72];
  int tid = threadIdx.x, lane = tid & 63, w = tid >> 6;
  int wr = w >> 1, wc = w & 1, c = lane & 15, g = lane >> 4;
  int rblk = blockIdx.x >> 2, cblk = blockIdx.x & 3;
  int R0 = rblk * 64, C0 = cblk * 64;
  int stride = (lens_raw[1] == 0 && lens_raw[3] == 0) ? 2 : 1;
  f32x4 acc[2][2] = {};
  for (int ks = 0; ks < 4; ++ks) {
    __syncthreads();
    #pragma unroll
    for (int it = 0; it < 2; ++it) {
      int task = tid + it * 256, row = task >> 3, ch = task & 7;
      *(u16x8*)(As + row * 72 + ch * 8) =
          *(const u16x8*)(a2 + (size_t)(R0 + row) * 256 + ks * 64 + ch * 8);
      *(u16x8*)(Bs + row * 72 + ch * 8) =
          *(const u16x8*)(Wo_t + (size_t)(C0 + row) * 256 + ks * 64 + ch * 8);
    }
    __syncthreads();
    #pragma unroll
    for (int kk = 0; kk < 2; ++kk) {
      int koff = kk * 32 + g * 8;
      bf16x8 af[2], bfr[2];
      #pragma unroll
      for (int rt = 0; rt < 2; ++rt) af[rt] = ld8(As + (wr * 32 + rt * 16 + c) * 72 + koff);
      #pragma unroll
      for (int ct = 0; ct < 2; ++ct) bfr[ct] = ld8(Bs + (wc * 32 + ct * 16 + c) * 72 + koff);
      #pragma unroll
      for (int rt = 0; rt < 2; ++rt)
        #pragma unroll
        for (int ct = 0; ct < 2; ++ct)
          acc[rt][ct] = mfma16(af[rt], bfr[ct], acc[rt][ct]);
    }
  }
  #pragma unroll
  for (int rt = 0; rt < 2; ++rt) {
    #pragma unroll
    for (int ct = 0; ct < 2; ++ct) {
      int F = C0 + wc * 32 + ct * 16 + c;
      float bo = b_o[F];
      #pragma unroll
      for (int rr = 0; rr < 4; ++rr) {
        int R = R0 + wr * 32 + rt * 16 + g * 4 + rr;
        int b = R >> 11, n = R & 2047;
        int Lb = lens_raw[b * stride];
        float val = acc[rt][ct][rr] + bo + x[(size_t)R * 256 + F];
        out[(size_t)R * 256 + F] = (n < Lb) ? val : 0.0f;
      }
    }
  }
}

// ---------------- launch ----------------
extern "C" void kernel_launch(void* const* d_in, const int* in_sizes, int n_in,
                              void* d_out, int out_size, void* d_ws, size_t ws_size,
                              hipStream_t stream) {
  const float* x        = (const float*)d_in[0];
  const float* W_uvqk   = (const float*)d_in[1];
  const float* b_uvqk   = (const float*)d_in[2];
  const float* W_o      = (const float*)d_in[3];
  const float* b_o      = (const float*)d_in[4];
  const float* ln_in_g  = (const float*)d_in[5];
  const float* ln_in_b  = (const float*)d_in[6];
  const float* ln_attn_g= (const float*)d_in[7];
  const float* ln_attn_b= (const float*)d_in[8];
  const float* w_pos    = (const float*)d_in[9];
  const float* w_ts     = (const float*)d_in[10];
  const int*   lengths  = (const int*)d_in[11];
  const int*   tstamps  = (const int*)d_in[12];
  float* out = (float*)d_out;

  char* ws = (char*)d_ws;
  size_t off = 0;
  auto alloc = [&](size_t bytes) -> void* {
    void* p = ws + off;
    off += (bytes + 255) & ~(size_t)255;
    return p;
  };
  unsigned short* Wu_t  = (unsigned short*)alloc(1024 * 256 * 2);
  unsigned short* Wo_t  = (unsigned short*)alloc(256 * 256 * 2);
  unsigned short* nx    = (unsigned short*)alloc((size_t)8192 * 256 * 2);
  float*          u     = (float*)alloc((size_t)8192 * 256 * 4);
  unsigned short* v_t   = (unsigned short*)alloc((size_t)8192 * 256 * 2);
  unsigned short* q_t   = (unsigned short*)alloc((size_t)8192 * 256 * 2);
  unsigned short* k_t   = (unsigned short*)alloc((size_t)8192 * 256 * 2);
  float*          avF   = (float*)alloc((size_t)8192 * 256 * 4);
  unsigned short* a2    = (unsigned short*)alloc((size_t)8192 * 256 * 2);
  // v_tmp is dead after k_vtrans; bias tiles (written later) overlay it.
  unsigned short* v_tmp = (unsigned short*)alloc((size_t)8192 * 256 * 2);
  unsigned short* bias_t = (unsigned short*)v_tmp;   // 4*2112*1024*2 B = 16.5 MB (extends past v_tmp)
  (void)alloc((size_t)4 * 2112 * 1024 * 2 - (size_t)8192 * 256 * 2);  // reserve the extension

  k_zero<<<2048, 256, 0, stream>>>(avF);
  k_prep_w<<<80, 256, 0, stream>>>(W_uvqk, W_o, Wu_t, Wo_t);
  k_ln_in<<<2048, 256, 0, stream>>>(x, ln_in_g, ln_in_b, nx);
  k_gemm_uvqk<<<512, 256, 0, stream>>>(nx, Wu_t, b_uvqk, u, v_tmp, q_t, k_t);
  k_vtrans<<<512, 256, 0, stream>>>(v_tmp, v_t);
  k_bias<<<16384, 256, 0, stream>>>(tstamps, lengths, w_pos, w_ts, bias_t);
  k_attn<<<4096, 256, 0, stream>>>(q_t, k_t, v_t, bias_t, lengths, avF);
  k_ln_attn<<<2048, 256, 0, stream>>>(avF, u, ln_attn_g, ln_attn_b, a2);
  k_gemm_out<<<512, 256, 0, stream>>>(a2, Wo_t, b_o, x, lengths, out);
}